// Round 12
// baseline (135.898 us; speedup 1.0000x reference)
//
#include <hip/hip_runtime.h>

#define N_NODES 50000
#define N_EDGES 600000
#define N_PAD   50048   // 782 * 64
#define IN_DIM 128
#define HID 256
#define OUT_DIM 64
#define MAX_DEG 64      // Poisson(12): P(deg>64) ~ 0
#define NBINS 196       // 256 nodes per bin (dst >> 8)
#define BCAP 4096       // per-bin region capacity
#define NPART 256       // partition-role blocks (R9 proven config)
#define ECHUNK 2344     // edges per partition block

typedef __attribute__((ext_vector_type(4))) float f32x4;
typedef __attribute__((ext_vector_type(8))) short short8;
typedef unsigned short u16;
typedef unsigned int u32;

__device__ __forceinline__ float bf2f(u32 lo16) {
  u32 u = lo16 << 16;
  return __builtin_bit_cast(float, u);
}
__device__ __forceinline__ u16 f2bf(float f) {
  u32 u = __builtin_bit_cast(u32, f);
  u = (u + 0x7FFF + ((u >> 16) & 1)) >> 16;
  return (u16)u;
}

// ---------------- fused prep + edge partition (R9 structure) ----------------
#define SEG0 (N_PAD * 16)
#define SEG1 (SEG0 + 128 * 64)
#define SEG2 (SEG1 + 64 * 64)
#define PREP_TOT SEG2

__global__ void k_prep_part(const float* __restrict__ x,
                            const float* __restrict__ W1l, const float* __restrict__ W1r,
                            const float* __restrict__ W2l, const float* __restrict__ W2r,
                            const int* __restrict__ src, const int* __restrict__ dst,
                            u16* __restrict__ xb, u16* __restrict__ W1p,
                            u16* __restrict__ W2p, u32* __restrict__ region,
                            int* __restrict__ gcur) {
  if (blockIdx.x < NPART) {
    __shared__ int hist[256];
    __shared__ int base[256];
    const int t = threadIdx.x;
    hist[t] = 0;
    __syncthreads();
    const int e0 = blockIdx.x * ECHUNK;
    const int e1 = min(e0 + ECHUNK, N_EDGES);
    for (int e = e0 + t; e < e1; e += 256) atomicAdd(&hist[dst[e] >> 8], 1);
    __syncthreads();
    base[t] = (hist[t] > 0) ? atomicAdd(&gcur[t], hist[t]) : 0;
    hist[t] = 0;
    __syncthreads();
    for (int e = e0 + t; e < e1; e += 256) {
      int d = dst[e];
      int bin = d >> 8;
      int idx = base[bin] + atomicAdd(&hist[bin], 1);
      if (idx < BCAP)
        region[(size_t)bin * BCAP + idx] = (u32)(src[e] & 0xffff) | ((u32)(d & 255) << 16);
    }
    return;
  }
  int idx = (blockIdx.x - NPART) * 256 + threadIdx.x;
  if (idx < SEG0) {
    int row = idx >> 4;
    int c8 = (idx & 15) * 8;
    short8 o;
    if (row < N_NODES) {
      f32x4 a = *(const f32x4*)&x[(size_t)row * 128 + c8];
      f32x4 b = *(const f32x4*)&x[(size_t)row * 128 + c8 + 4];
      o[0] = (short)f2bf(a[0]); o[1] = (short)f2bf(a[1]);
      o[2] = (short)f2bf(a[2]); o[3] = (short)f2bf(a[3]);
      o[4] = (short)f2bf(b[0]); o[5] = (short)f2bf(b[1]);
      o[6] = (short)f2bf(b[2]); o[7] = (short)f2bf(b[3]);
    } else {
      for (int j = 0; j < 8; ++j) o[j] = 0;
    }
    *(short8*)&xb[(size_t)row * 128 + c8] = o;
  } else if (idx < SEG1) {
    int i = idx - SEG0;
    int F = i >> 6, l = i & 63;
    int wch = F >> 6, kt = (F >> 4) & 3, kk = (F >> 3) & 1, n = F & 7;
    int row = wch * 128 + n * 16 + (l & 15);
    int kb = kt * 64 + kk * 32 + (l >> 4) * 8;
    short8 o;
#pragma unroll
    for (int j = 0; j < 8; ++j) {
      int k = kb + j;
      float v = (k < 128) ? W1l[(size_t)k * HID + row] : W1r[(size_t)(k - 128) * HID + row];
      o[j] = (short)f2bf(v);
    }
    *(short8*)&W1p[(size_t)i * 8] = o;
  } else if (idx < SEG2) {
    int i = idx - SEG1;
    int G = i >> 6, l = i & 63;
    int wch = G >> 5, kk = (G >> 2) & 7, n = G & 3;
    int row = wch * 64 + n * 16 + (l & 15);
    int kb = kk * 32 + (l >> 4) * 8;
    short8 o;
#pragma unroll
    for (int j = 0; j < 8; ++j) {
      int k = kb + j;
      float v = (row < 64) ? W2l[(size_t)k * OUT_DIM + row]
                           : W2r[(size_t)k * OUT_DIM + (row - 64)];
      o[j] = (short)f2bf(v);
    }
    *(short8*)&W2p[(size_t)i * 8] = o;
  }
}

// ---------------- bucket build: one block per bin, LDS atomics only ----------------

__global__ __launch_bounds__(256) void k_build(const u32* __restrict__ region,
                                               const int* __restrict__ gcur,
                                               int* __restrict__ cnt,
                                               u16* __restrict__ bucket) {
  __shared__ u16 lbkt[256 * 64];
  __shared__ int lcnt[256];
  const int t = threadIdx.x;
  const int bin = blockIdx.x;
  lcnt[t] = 0;
  __syncthreads();
  int n = gcur[bin];
  if (n > BCAP) n = BCAP;
  for (int i = t; i < n; i += 256) {
    u32 r = region[(size_t)bin * BCAP + i];
    int dl = (r >> 16) & 255;
    int pos = atomicAdd(&lcnt[dl], 1);
    if (pos < MAX_DEG) lbkt[dl * 64 + pos] = (u16)(r & 0xffff);
  }
  __syncthreads();
  int gnode = bin * 256 + t;
  if (gnode < N_NODES) cnt[gnode] = lcnt[t];
  for (int i = t; i < 2048; i += 256) {
    int nl = i >> 3, sub = i & 7;
    int gn = bin * 256 + nl;
    if (gn < N_NODES)
      *(short8*)&bucket[(size_t)gn * 64 + sub * 8] = *(const short8*)&lbkt[nl * 64 + sub * 8];
  }
}

// ---------------- fused aggregate + MLP: per 64-row block ----------------
// phase 0: prefetch xb K-tiles (global_load_lds, latency hidden under gather);
//          gather+mean 64 nodes -> bf16 -> LDS ags (As-layout swizzle).
// phase 1: h[64][256] = relu([ags|As] @ W1p + b1) -> hs (aliases ags; barrier-safe:
//          ags dead after kt=1 reads, hs written after kt loop, 1 barrier between).
// phase 2: p|q = h @ W2p -> pb, qb.  LDS 48KB -> 3 blocks/CU. 3 barriers total.

__device__ __forceinline__ void gl_lds16(const void* g, void* l) {
  __builtin_amdgcn_global_load_lds((const __attribute__((address_space(1))) u32*)g,
                                   (__attribute__((address_space(3))) u32*)l, 16, 0, 0);
}

__global__ __launch_bounds__(256, 3) void k_agg_mlp(
    const u16* __restrict__ xb, const int* __restrict__ cnt,
    const u16* __restrict__ bucket,
    const u16* __restrict__ W1p, const u16* __restrict__ W2p,
    const float* __restrict__ b1, u16* __restrict__ pb, u16* __restrict__ qb) {
  __shared__ u16 un[64 * 256];    // 32KB: [0,16KB)=ags (phase 0/1), then hs (phase 1.5/2)
  __shared__ u16 As[2][64 * 64];  // 16KB: xb K-tiles, staged at entry
  const int t = threadIdx.x;
  const int wave = t >> 6;
  const int lane = t & 63;
  const int brow = blockIdx.x * 64;
  const int lr = lane & 15;
  const int kg = lane >> 4;
  const int wch = wave & 1;

  // ---- phase 0a: prefetch xb K-tiles into As[0], As[1] ----
#pragma unroll
  for (int b = 0; b < 2; ++b) {
    const int koff = b * 64;
#pragma unroll
    for (int i = 0; i < 2; ++i) {
      int chunk = wave * 2 + i;
      int f = chunk * 1024 + lane * 16;
      int row = f >> 7;
      int cbs = (f & 127) ^ ((row & 7) << 4);
      gl_lds16(&xb[(size_t)(brow + row) * 128 + koff + (cbs >> 1)],
               (char*)As[b] + chunk * 1024);
    }
  }

  // ---- phase 0b: gather+mean, 16 nodes per wave, results -> ags ----
  {
    const int es = lane >> 4, dl = lane & 15;
    for (int nl = 0; nl < 16; ++nl) {
      int rowloc = wave * 16 + nl;
      int node = brow + rowloc;
      int deg = (node < N_NODES) ? cnt[node] : 0;
      int sreg = (node < N_NODES) ? (int)bucket[(size_t)node * MAX_DEG + lane] : 0;
      float acc[8] = {0.f, 0.f, 0.f, 0.f, 0.f, 0.f, 0.f, 0.f};
      short8 pend = (short8){0, 0, 0, 0, 0, 0, 0, 0};
      for (int e = 0; e < deg; e += 4) {
        int ee = e + es;
        int s = __shfl(sreg, ee & 63);  // full-wave active (EXEC rule)
        short8 v = (short8){0, 0, 0, 0, 0, 0, 0, 0};
        if (ee < deg) v = *(const short8*)&xb[(size_t)s * 128 + dl * 8];
#pragma unroll
        for (int j = 0; j < 8; ++j) acc[j] += bf2f((u16)pend[j]);
        pend = v;
      }
#pragma unroll
      for (int j = 0; j < 8; ++j) acc[j] += bf2f((u16)pend[j]);
#pragma unroll
      for (int j = 0; j < 8; ++j) {
        acc[j] += __shfl_xor(acc[j], 16);
        acc[j] += __shfl_xor(acc[j], 32);
      }
      float inv = 1.f / fmaxf((float)deg, 1.f);
      if (es == 0) {
        short8 o;
#pragma unroll
        for (int j = 0; j < 8; ++j) o[j] = (short)f2bf(acc[j] * inv);
        // dims dl*8..dl*8+7 -> tile b = dl>>3, byte col = (dl&7)*16, As-swizzle
        int b = dl >> 3, colb = (dl & 7) * 16;
        *(short8*)((char*)un + b * 8192 + rowloc * 128 + (colb ^ ((rowloc & 7) << 4))) = o;
      }
    }
  }
  __syncthreads();  // ags complete; xb prefetch drained (vmcnt(0) at barrier)

  // ---- phase 1: wave tile 32 rows x 128 cols, K=256, no barriers in loop ----
  const int wr = (wave >> 1) * 32;
  const int wc = wch * 128;

  f32x4 acc1[2][8];
#pragma unroll
  for (int m = 0; m < 2; ++m)
#pragma unroll
    for (int n = 0; n < 8; ++n) acc1[m][n] = (f32x4){0.f, 0.f, 0.f, 0.f};

#pragma unroll
  for (int kt = 0; kt < 4; ++kt) {
    const char* asrc = (kt < 2) ? ((const char*)un + kt * 8192) : (const char*)As[kt - 2];
#pragma unroll
    for (int kk = 0; kk < 2; ++kk) {
      short8 af[2], bfr[8];
      const int cb = kk * 64 + kg * 16;
#pragma unroll
      for (int m = 0; m < 2; ++m) {
        int row = wr + m * 16 + lr;
        af[m] = *(const short8*)(asrc + row * 128 + (cb ^ ((row & 7) << 4)));
      }
#pragma unroll
      for (int n = 0; n < 8; ++n)
        bfr[n] = *(const short8*)&W1p[(size_t)(((wch * 4 + kt) * 2 + kk) * 8 + n) * 512 +
                                      lane * 8];
#pragma unroll
      for (int m = 0; m < 2; ++m)
#pragma unroll
        for (int n = 0; n < 8; ++n)
          acc1[m][n] =
              __builtin_amdgcn_mfma_f32_16x16x32_bf16(af[m], bfr[n], acc1[m][n], 0, 0, 0);
    }
  }
  __syncthreads();  // all ags reads done before hs overwrite

  // ---- phase 1 epilogue: h -> hs (512B-stride rows, XOR-swizzled) ----
#pragma unroll
  for (int n = 0; n < 8; ++n) {
    int col = wc + n * 16 + lr;
    float bv = b1[col];
#pragma unroll
    for (int m = 0; m < 2; ++m) {
#pragma unroll
      for (int j = 0; j < 4; ++j) {
        int row = wr + kg * 4 + m * 16 + j;
        float v = fmaxf(acc1[m][n][j] + bv, 0.f);
        *(u16*)((char*)un + row * 512 + ((col * 2) ^ ((row & 7) << 4))) = f2bf(v);
      }
    }
  }
  __syncthreads();

  // ---- phase 2: wave tile 32 rows x 64 cols; K=256 from hs; B from W2p ----
  const int wr2 = (wave >> 1) * 32;
  f32x4 acc2[2][4];
#pragma unroll
  for (int m = 0; m < 2; ++m)
#pragma unroll
    for (int n = 0; n < 4; ++n) acc2[m][n] = (f32x4){0.f, 0.f, 0.f, 0.f};

#pragma unroll
  for (int kk = 0; kk < 8; ++kk) {
    const int cb = kk * 64 + kg * 16;
    short8 af[2], bfr[4];
#pragma unroll
    for (int m = 0; m < 2; ++m) {
      int row = wr2 + m * 16 + lr;
      af[m] = *(const short8*)((const char*)un + row * 512 + (cb ^ ((row & 7) << 4)));
    }
#pragma unroll
    for (int n = 0; n < 4; ++n)
      bfr[n] = *(const short8*)&W2p[(size_t)((wch * 8 + kk) * 4 + n) * 512 + lane * 8];
#pragma unroll
    for (int m = 0; m < 2; ++m)
#pragma unroll
      for (int n = 0; n < 4; ++n)
        acc2[m][n] =
            __builtin_amdgcn_mfma_f32_16x16x32_bf16(af[m], bfr[n], acc2[m][n], 0, 0, 0);
  }

  u16* outb = wch ? qb : pb;
#pragma unroll
  for (int n = 0; n < 4; ++n) {
    int col = n * 16 + lr;
#pragma unroll
    for (int m = 0; m < 2; ++m) {
#pragma unroll
      for (int j = 0; j < 4; ++j) {
        int row = brow + wr2 + kg * 4 + m * 16 + j;
        outb[(size_t)row * 64 + col] = f2bf(acc2[m][n][j]);
      }
    }
  }
}

// ---------------- output: out = mean_agg(pb) + qb + b2 (R9 structure) ----------------

__global__ void k_out(const u16* __restrict__ pb, const u16* __restrict__ qb,
                      const int* __restrict__ cnt, const u16* __restrict__ bucket,
                      const float* __restrict__ b2, float* __restrict__ out) {
  int node = blockIdx.x * 4 + (threadIdx.x >> 6);
  if (node >= N_NODES) return;
  int lane = threadIdx.x & 63;
  int es = lane >> 3, dl = lane & 7;
  int deg = cnt[node];
  int sreg = (int)bucket[(size_t)node * MAX_DEG + lane];
  float acc[8] = {0.f, 0.f, 0.f, 0.f, 0.f, 0.f, 0.f, 0.f};
  short8 pend = (short8){0, 0, 0, 0, 0, 0, 0, 0};
  for (int e = 0; e < deg; e += 8) {
    int ee = e + es;
    int s = __shfl(sreg, ee & 63);  // full-wave active
    short8 v = (short8){0, 0, 0, 0, 0, 0, 0, 0};
    if (ee < deg) v = *(const short8*)&pb[(size_t)s * 64 + dl * 8];
#pragma unroll
    for (int j = 0; j < 8; ++j) acc[j] += bf2f((u16)pend[j]);
    pend = v;
  }
#pragma unroll
  for (int j = 0; j < 8; ++j) acc[j] += bf2f((u16)pend[j]);
#pragma unroll
  for (int j = 0; j < 8; ++j) {
    acc[j] += __shfl_xor(acc[j], 8);
    acc[j] += __shfl_xor(acc[j], 16);
    acc[j] += __shfl_xor(acc[j], 32);
  }
  float inv = 1.f / fmaxf((float)deg, 1.f);
  if (es == 0) {
    short8 q = *(const short8*)&qb[(size_t)node * 64 + dl * 8];
    f32x4 bb0 = *(const f32x4*)&b2[dl * 8];
    f32x4 bb1 = *(const f32x4*)&b2[dl * 8 + 4];
    f32x4 o0, o1;
#pragma unroll
    for (int j = 0; j < 4; ++j) {
      o0[j] = acc[j] * inv + bf2f((u16)q[j]) + bb0[j];
      o1[j] = acc[j + 4] * inv + bf2f((u16)q[j + 4]) + bb1[j];
    }
    *(f32x4*)&out[(size_t)node * 64 + dl * 8] = o0;
    *(f32x4*)&out[(size_t)node * 64 + dl * 8 + 4] = o1;
  }
}

// ---------------- launch ----------------

extern "C" void kernel_launch(void* const* d_in, const int* in_sizes, int n_in,
                              void* d_out, int out_size, void* d_ws, size_t ws_size,
                              hipStream_t stream) {
  const float* x   = (const float*)d_in[0];
  const int*   ei  = (const int*)d_in[1];
  const float* W1l = (const float*)d_in[2];
  const float* W1r = (const float*)d_in[3];
  const float* b1  = (const float*)d_in[4];
  const float* W2l = (const float*)d_in[5];
  const float* W2r = (const float*)d_in[6];
  const float* b2  = (const float*)d_in[7];
  float* out = (float*)d_out;

  const int* src = ei;
  const int* dst = ei + N_EDGES;

  char* ws = (char*)d_ws;
  size_t off = 0;
  auto alloc = [&](size_t bytes) -> void* {
    void* p = ws + off;
    off = (off + bytes + 255) & ~(size_t)255;
    return p;
  };
  int* gcur   = (int*)alloc(256 * 4);
  u32* region = (u32*)alloc((size_t)NBINS * BCAP * 4);
  int* cnt    = (int*)alloc((size_t)N_NODES * 4);
  u16* bucket = (u16*)alloc((size_t)N_NODES * MAX_DEG * 2);
  u16* xb     = (u16*)alloc((size_t)N_PAD * 128 * 2);
  u16* W1p    = (u16*)alloc((size_t)128 * 64 * 8 * 2);
  u16* W2p    = (u16*)alloc((size_t)64 * 64 * 8 * 2);
  u16* pb     = (u16*)alloc((size_t)N_PAD * 64 * 2);
  u16* qb     = (u16*)alloc((size_t)N_PAD * 64 * 2);

  hipMemsetAsync(gcur, 0, 256 * 4, stream);

  int blocks = NPART + (PREP_TOT + 255) / 256;
  k_prep_part<<<blocks, 256, 0, stream>>>(x, W1l, W1r, W2l, W2r, src, dst,
                                          xb, W1p, W2p, region, gcur);
  k_build<<<NBINS, 256, 0, stream>>>(region, gcur, cnt, bucket);
  k_agg_mlp<<<N_PAD / 64, 256, 0, stream>>>(xb, cnt, bucket, W1p, W2p, b1, pb, qb);
  k_out<<<(N_NODES + 3) / 4, 256, 0, stream>>>(pb, qb, cnt, bucket, b2, out);
}

// Round 13
// 99.146 us; speedup vs baseline: 1.3707x; 1.3707x over previous
//
#include <hip/hip_runtime.h>

#define N_NODES 50000
#define N_EDGES 600000
#define N_PAD   50048   // 782 * 64
#define IN_DIM 128
#define HID 256
#define OUT_DIM 64
#define MAX_DEG 64      // Poisson(12): P(deg>64) ~ 0
#define NBINS 196       // 256 nodes per bin (dst >> 8)
#define BCAP 4096       // per-bin region capacity
#define NPART 256       // partition-role blocks (best-measured config, R9)
#define ECHUNK 2344     // edges per partition block (256*2344 >= 600000)
#define EPT 10          // edges per thread in partition role (ceil(2344/256))

typedef __attribute__((ext_vector_type(4))) float f32x4;
typedef __attribute__((ext_vector_type(8))) short short8;
typedef unsigned short u16;
typedef unsigned int u32;

__device__ __forceinline__ float bf2f(u32 lo16) {
  u32 u = lo16 << 16;
  return __builtin_bit_cast(float, u);
}
__device__ __forceinline__ u16 f2bf(float f) {
  u32 u = __builtin_bit_cast(u32, f);
  u = (u + 0x7FFF + ((u >> 16) & 1)) >> 16;
  return (u16)u;
}

// ---------------- fused prep + edge partition ----------------
// partition: LDS histogram over 196 dst-bins, ONE global atomic per
// (block,bin), then plain scatter of packed records (src:16|dstlow:8).
// (d,s) register-cached across the two passes (fixed-trip unrolled loop,
// compile-time indices -> stays in VGPRs), so dst/src are read ONCE.
#define SEG0 (N_PAD * 16)
#define SEG1 (SEG0 + 128 * 64)
#define SEG2 (SEG1 + 64 * 64)
#define PREP_TOT SEG2

__global__ void k_prep_part(const float* __restrict__ x,
                            const float* __restrict__ W1l, const float* __restrict__ W1r,
                            const float* __restrict__ W2l, const float* __restrict__ W2r,
                            const int* __restrict__ src, const int* __restrict__ dst,
                            u16* __restrict__ xb, u16* __restrict__ W1p,
                            u16* __restrict__ W2p, u32* __restrict__ region,
                            int* __restrict__ gcur) {
  if (blockIdx.x < NPART) {
    __shared__ int hist[256];
    __shared__ int base[256];
    const int t = threadIdx.x;
    hist[t] = 0;
    __syncthreads();
    const int e0 = blockIdx.x * ECHUNK;
    const int e1 = min(e0 + ECHUNK, N_EDGES);
    int dv[EPT], sv[EPT];
#pragma unroll
    for (int i = 0; i < EPT; ++i) {
      int e = e0 + t + i * 256;
      int ok = (e < e1);
      dv[i] = ok ? dst[e] : -1;
      sv[i] = ok ? src[e] : 0;
      if (ok) atomicAdd(&hist[dv[i] >> 8], 1);
    }
    __syncthreads();
    base[t] = (hist[t] > 0) ? atomicAdd(&gcur[t], hist[t]) : 0;
    hist[t] = 0;
    __syncthreads();
#pragma unroll
    for (int i = 0; i < EPT; ++i) {
      int d = dv[i];
      if (d >= 0) {
        int bin = d >> 8;
        int idx = base[bin] + atomicAdd(&hist[bin], 1);
        if (idx < BCAP)
          region[(size_t)bin * BCAP + idx] = (u32)(sv[i] & 0xffff) | ((u32)(d & 255) << 16);
      }
    }
    return;
  }
  int idx = (blockIdx.x - NPART) * 256 + threadIdx.x;
  if (idx < SEG0) {
    int row = idx >> 4;
    int c8 = (idx & 15) * 8;
    short8 o;
    if (row < N_NODES) {
      f32x4 a = *(const f32x4*)&x[(size_t)row * 128 + c8];
      f32x4 b = *(const f32x4*)&x[(size_t)row * 128 + c8 + 4];
      o[0] = (short)f2bf(a[0]); o[1] = (short)f2bf(a[1]);
      o[2] = (short)f2bf(a[2]); o[3] = (short)f2bf(a[3]);
      o[4] = (short)f2bf(b[0]); o[5] = (short)f2bf(b[1]);
      o[6] = (short)f2bf(b[2]); o[7] = (short)f2bf(b[3]);
    } else {
      for (int j = 0; j < 8; ++j) o[j] = 0;
    }
    *(short8*)&xb[(size_t)row * 128 + c8] = o;
  } else if (idx < SEG1) {
    int i = idx - SEG0;
    int F = i >> 6, l = i & 63;
    int wch = F >> 6, kt = (F >> 4) & 3, kk = (F >> 3) & 1, n = F & 7;
    int row = wch * 128 + n * 16 + (l & 15);
    int kb = kt * 64 + kk * 32 + (l >> 4) * 8;
    short8 o;
#pragma unroll
    for (int j = 0; j < 8; ++j) {
      int k = kb + j;
      float v = (k < 128) ? W1l[(size_t)k * HID + row] : W1r[(size_t)(k - 128) * HID + row];
      o[j] = (short)f2bf(v);
    }
    *(short8*)&W1p[(size_t)i * 8] = o;
  } else if (idx < SEG2) {
    int i = idx - SEG1;
    int G = i >> 6, l = i & 63;
    int wch = G >> 5, kk = (G >> 2) & 7, n = G & 3;
    int row = wch * 64 + n * 16 + (l & 15);
    int kb = kk * 32 + (l >> 4) * 8;
    short8 o;
#pragma unroll
    for (int j = 0; j < 8; ++j) {
      int k = kb + j;
      float v = (row < 64) ? W2l[(size_t)k * OUT_DIM + row]
                           : W2r[(size_t)k * OUT_DIM + (row - 64)];
      o[j] = (short)f2bf(v);
    }
    *(short8*)&W2p[(size_t)i * 8] = o;
  }
}

// ---------------- bucket build: one block per bin, LDS atomics only ----------------

__global__ __launch_bounds__(256) void k_build(const u32* __restrict__ region,
                                               const int* __restrict__ gcur,
                                               int* __restrict__ cnt,
                                               u16* __restrict__ bucket) {
  __shared__ u16 lbkt[256 * 64];
  __shared__ int lcnt[256];
  const int t = threadIdx.x;
  const int bin = blockIdx.x;
  lcnt[t] = 0;
  __syncthreads();
  int n = gcur[bin];
  if (n > BCAP) n = BCAP;
  for (int i = t; i < n; i += 256) {
    u32 r = region[(size_t)bin * BCAP + i];
    int dl = (r >> 16) & 255;
    int pos = atomicAdd(&lcnt[dl], 1);
    if (pos < MAX_DEG) lbkt[dl * 64 + pos] = (u16)(r & 0xffff);
  }
  __syncthreads();
  int gnode = bin * 256 + t;
  if (gnode < N_NODES) cnt[gnode] = lcnt[t];
  for (int i = t; i < 2048; i += 256) {
    int nl = i >> 3, sub = i & 7;
    int gn = bin * 256 + nl;
    if (gn < N_NODES)
      *(short8*)&bucket[(size_t)gn * 64 + sub * 8] = *(const short8*)&lbkt[nl * 64 + sub * 8];
  }
}

// ---------------- layer-1 mean aggregation: one wave per node ----------------
// 4 edge-slots x 16 dim-chunks; shfl outside guard (EXEC rule); 1-deep pipeline.

__global__ void k_agg(const u16* __restrict__ xb, const int* __restrict__ cnt,
                      const u16* __restrict__ bucket, u16* __restrict__ agg) {
  int node = blockIdx.x * 4 + (threadIdx.x >> 6);
  if (node >= N_PAD) return;
  int lane = threadIdx.x & 63;
  int es = lane >> 4, dl = lane & 15;
  int deg = (node < N_NODES) ? cnt[node] : 0;
  int sreg = (node < N_NODES) ? (int)bucket[(size_t)node * MAX_DEG + lane] : 0;
  float acc[8] = {0.f, 0.f, 0.f, 0.f, 0.f, 0.f, 0.f, 0.f};
  short8 pend = (short8){0, 0, 0, 0, 0, 0, 0, 0};
  for (int e = 0; e < deg; e += 4) {
    int ee = e + es;
    int s = __shfl(sreg, ee & 63);  // full-wave active
    short8 v = (short8){0, 0, 0, 0, 0, 0, 0, 0};
    if (ee < deg) v = *(const short8*)&xb[(size_t)s * 128 + dl * 8];
#pragma unroll
    for (int j = 0; j < 8; ++j) acc[j] += bf2f((u16)pend[j]);
    pend = v;
  }
#pragma unroll
  for (int j = 0; j < 8; ++j) acc[j] += bf2f((u16)pend[j]);
#pragma unroll
  for (int j = 0; j < 8; ++j) {
    acc[j] += __shfl_xor(acc[j], 16);
    acc[j] += __shfl_xor(acc[j], 32);
  }
  float inv = 1.f / fmaxf((float)deg, 1.f);
  if (es == 0) {
    short8 o;
#pragma unroll
    for (int j = 0; j < 8; ++j) o[j] = (short)f2bf(acc[j] * inv);
    *(short8*)&agg[(size_t)node * 128 + dl * 8] = o;
  }
}

// ---------------- fused MLP ----------------

__device__ __forceinline__ void gl_lds16(const void* g, void* l) {
  __builtin_amdgcn_global_load_lds((const __attribute__((address_space(1))) u32*)g,
                                   (__attribute__((address_space(3))) u32*)l, 16, 0, 0);
}

__global__ __launch_bounds__(256, 3) void k_mlp(
    const u16* __restrict__ agg, const u16* __restrict__ xb,
    const u16* __restrict__ W1p, const u16* __restrict__ W2p,
    const float* __restrict__ b1, u16* __restrict__ pb, u16* __restrict__ qb) {
  __shared__ u16 hs[64 * 256];
  __shared__ u16 As[2][64 * 64];
  const int t = threadIdx.x;
  const int wave = t >> 6;
  const int lane = t & 63;
  const int brow = blockIdx.x * 64;
  const int lr = lane & 15;
  const int kg = lane >> 4;
  const int wch = wave & 1;

  const int wr = (wave >> 1) * 32;
  const int wc = wch * 128;

  f32x4 acc[2][8];
#pragma unroll
  for (int m = 0; m < 2; ++m)
#pragma unroll
    for (int n = 0; n < 8; ++n) acc[m][n] = (f32x4){0.f, 0.f, 0.f, 0.f};

  auto stageA = [&](int buf, int kt) {
    const u16* base = (kt < 2) ? agg : xb;
    const int koff = (kt & 1) * 64;
#pragma unroll
    for (int i = 0; i < 2; ++i) {
      int chunk = wave * 2 + i;
      int f = chunk * 1024 + lane * 16;
      int row = f >> 7;
      int cbs = (f & 127) ^ ((row & 7) << 4);
      gl_lds16(&base[(size_t)(brow + row) * 128 + koff + (cbs >> 1)],
               (char*)As[buf] + chunk * 1024);
    }
  };

  stageA(0, 0);
  __syncthreads();

#pragma unroll
  for (int kt = 0; kt < 4; ++kt) {
    const int cur = kt & 1;
    if (kt < 3) stageA(cur ^ 1, kt + 1);
#pragma unroll
    for (int kk = 0; kk < 2; ++kk) {
      short8 af[2], bfr[8];
      const int cb = kk * 64 + kg * 16;
#pragma unroll
      for (int m = 0; m < 2; ++m) {
        int row = wr + m * 16 + lr;
        af[m] = *(const short8*)((const char*)As[cur] + row * 128 + (cb ^ ((row & 7) << 4)));
      }
#pragma unroll
      for (int n = 0; n < 8; ++n)
        bfr[n] = *(const short8*)&W1p[(size_t)(((wch * 4 + kt) * 2 + kk) * 8 + n) * 512 +
                                      lane * 8];
#pragma unroll
      for (int m = 0; m < 2; ++m)
#pragma unroll
        for (int n = 0; n < 8; ++n)
          acc[m][n] =
              __builtin_amdgcn_mfma_f32_16x16x32_bf16(af[m], bfr[n], acc[m][n], 0, 0, 0);
    }
    __syncthreads();
  }

#pragma unroll
  for (int n = 0; n < 8; ++n) {
    int col = wc + n * 16 + lr;
    float bv = b1[col];
#pragma unroll
    for (int m = 0; m < 2; ++m) {
#pragma unroll
      for (int j = 0; j < 4; ++j) {
        int row = wr + kg * 4 + m * 16 + j;
        float v = fmaxf(acc[m][n][j] + bv, 0.f);
        *(u16*)((char*)hs + row * 512 + ((col * 2) ^ ((row & 7) << 4))) = f2bf(v);
      }
    }
  }
  __syncthreads();

  const int wr2 = (wave >> 1) * 32;
  f32x4 acc2[2][4];
#pragma unroll
  for (int m = 0; m < 2; ++m)
#pragma unroll
    for (int n = 0; n < 4; ++n) acc2[m][n] = (f32x4){0.f, 0.f, 0.f, 0.f};

#pragma unroll
  for (int kk = 0; kk < 8; ++kk) {
    const int cb = kk * 64 + kg * 16;
    short8 af[2], bfr[4];
#pragma unroll
    for (int m = 0; m < 2; ++m) {
      int row = wr2 + m * 16 + lr;
      af[m] = *(const short8*)((const char*)hs + row * 512 + (cb ^ ((row & 7) << 4)));
    }
#pragma unroll
    for (int n = 0; n < 4; ++n)
      bfr[n] = *(const short8*)&W2p[(size_t)((wch * 8 + kk) * 4 + n) * 512 + lane * 8];
#pragma unroll
    for (int m = 0; m < 2; ++m)
#pragma unroll
      for (int n = 0; n < 4; ++n)
        acc2[m][n] =
            __builtin_amdgcn_mfma_f32_16x16x32_bf16(af[m], bfr[n], acc2[m][n], 0, 0, 0);
  }

  u16* outb = wch ? qb : pb;
#pragma unroll
  for (int n = 0; n < 4; ++n) {
    int col = n * 16 + lr;
#pragma unroll
    for (int m = 0; m < 2; ++m) {
#pragma unroll
      for (int j = 0; j < 4; ++j) {
        int row = brow + wr2 + kg * 4 + m * 16 + j;
        outb[(size_t)row * 64 + col] = f2bf(acc2[m][n][j]);
      }
    }
  }
}

// ---------------- output: out = mean_agg(pb) + qb + b2, one wave per node ----------------
// 8 edge-slots x 8 dim-chunks; shfl outside guard; 1-deep pipeline.

__global__ void k_out(const u16* __restrict__ pb, const u16* __restrict__ qb,
                      const int* __restrict__ cnt, const u16* __restrict__ bucket,
                      const float* __restrict__ b2, float* __restrict__ out) {
  int node = blockIdx.x * 4 + (threadIdx.x >> 6);
  if (node >= N_NODES) return;
  int lane = threadIdx.x & 63;
  int es = lane >> 3, dl = lane & 7;
  int deg = cnt[node];
  int sreg = (int)bucket[(size_t)node * MAX_DEG + lane];
  float acc[8] = {0.f, 0.f, 0.f, 0.f, 0.f, 0.f, 0.f, 0.f};
  short8 pend = (short8){0, 0, 0, 0, 0, 0, 0, 0};
  for (int e = 0; e < deg; e += 8) {
    int ee = e + es;
    int s = __shfl(sreg, ee & 63);  // full-wave active
    short8 v = (short8){0, 0, 0, 0, 0, 0, 0, 0};
    if (ee < deg) v = *(const short8*)&pb[(size_t)s * 64 + dl * 8];
#pragma unroll
    for (int j = 0; j < 8; ++j) acc[j] += bf2f((u16)pend[j]);
    pend = v;
  }
#pragma unroll
  for (int j = 0; j < 8; ++j) acc[j] += bf2f((u16)pend[j]);
#pragma unroll
  for (int j = 0; j < 8; ++j) {
    acc[j] += __shfl_xor(acc[j], 8);
    acc[j] += __shfl_xor(acc[j], 16);
    acc[j] += __shfl_xor(acc[j], 32);
  }
  float inv = 1.f / fmaxf((float)deg, 1.f);
  if (es == 0) {
    short8 q = *(const short8*)&qb[(size_t)node * 64 + dl * 8];
    f32x4 bb0 = *(const f32x4*)&b2[dl * 8];
    f32x4 bb1 = *(const f32x4*)&b2[dl * 8 + 4];
    f32x4 o0, o1;
#pragma unroll
    for (int j = 0; j < 4; ++j) {
      o0[j] = acc[j] * inv + bf2f((u16)q[j]) + bb0[j];
      o1[j] = acc[j + 4] * inv + bf2f((u16)q[j + 4]) + bb1[j];
    }
    *(f32x4*)&out[(size_t)node * 64 + dl * 8] = o0;
    *(f32x4*)&out[(size_t)node * 64 + dl * 8 + 4] = o1;
  }
}

// ---------------- launch ----------------

extern "C" void kernel_launch(void* const* d_in, const int* in_sizes, int n_in,
                              void* d_out, int out_size, void* d_ws, size_t ws_size,
                              hipStream_t stream) {
  const float* x   = (const float*)d_in[0];
  const int*   ei  = (const int*)d_in[1];
  const float* W1l = (const float*)d_in[2];
  const float* W1r = (const float*)d_in[3];
  const float* b1  = (const float*)d_in[4];
  const float* W2l = (const float*)d_in[5];
  const float* W2r = (const float*)d_in[6];
  const float* b2  = (const float*)d_in[7];
  float* out = (float*)d_out;

  const int* src = ei;
  const int* dst = ei + N_EDGES;

  char* ws = (char*)d_ws;
  size_t off = 0;
  auto alloc = [&](size_t bytes) -> void* {
    void* p = ws + off;
    off = (off + bytes + 255) & ~(size_t)255;
    return p;
  };
  int* gcur   = (int*)alloc(256 * 4);
  u32* region = (u32*)alloc((size_t)NBINS * BCAP * 4);
  int* cnt    = (int*)alloc((size_t)N_NODES * 4);
  u16* bucket = (u16*)alloc((size_t)N_NODES * MAX_DEG * 2);
  u16* xb     = (u16*)alloc((size_t)N_PAD * 128 * 2);
  u16* agg    = (u16*)alloc((size_t)N_PAD * 128 * 2);
  u16* W1p    = (u16*)alloc((size_t)128 * 64 * 8 * 2);
  u16* W2p    = (u16*)alloc((size_t)64 * 64 * 8 * 2);
  u16* pb     = (u16*)alloc((size_t)N_PAD * 64 * 2);
  u16* qb     = (u16*)alloc((size_t)N_PAD * 64 * 2);

  hipMemsetAsync(gcur, 0, 256 * 4, stream);

  int blocks = NPART + (PREP_TOT + 255) / 256;
  k_prep_part<<<blocks, 256, 0, stream>>>(x, W1l, W1r, W2l, W2r, src, dst,
                                          xb, W1p, W2p, region, gcur);
  k_build<<<NBINS, 256, 0, stream>>>(region, gcur, cnt, bucket);
  k_agg<<<N_PAD / 4, 256, 0, stream>>>(xb, cnt, bucket, agg);
  k_mlp<<<N_PAD / 64, 256, 0, stream>>>(agg, xb, W1p, W2p, b1, pb, qb);
  k_out<<<(N_NODES + 3) / 4, 256, 0, stream>>>(pb, qb, cnt, bucket, b2, out);
}

// Round 14
// 98.842 us; speedup vs baseline: 1.3749x; 1.0031x over previous
//
#include <hip/hip_runtime.h>

#define N_NODES 50000
#define N_EDGES 600000
#define N_PAD   50048   // 782 * 64
#define IN_DIM 128
#define HID 256
#define OUT_DIM 64
#define MAX_DEG 64      // Poisson(12): P(deg>64) ~ 0
#define NBINS 196       // 256 nodes per bin (dst >> 8)
#define BCAP 4096       // per-bin region capacity
#define NPART 256       // partition-role blocks
#define ECHUNK 2344     // edges per partition block (256*2344 >= 600000)
#define EPT 10          // edges per thread in partition role

typedef __attribute__((ext_vector_type(4))) float f32x4;
typedef __attribute__((ext_vector_type(8))) short short8;
typedef unsigned short u16;
typedef unsigned int u32;

__device__ __forceinline__ float bf2f(u32 lo16) {
  u32 u = lo16 << 16;
  return __builtin_bit_cast(float, u);
}
__device__ __forceinline__ u16 f2bf(float f) {
  u32 u = __builtin_bit_cast(u32, f);
  u = (u + 0x7FFF + ((u >> 16) & 1)) >> 16;
  return (u16)u;
}

// ---------------- gcur zero: replaces hipMemsetAsync ----------------
// R13 profile showed the runtime's fillBufferAligned for the 1KB memset
// costing ~42us per replay inside the graph. A plain 1-block kernel is ~2us.

__global__ void k_zero_gcur(int* __restrict__ gcur) {
  gcur[threadIdx.x] = 0;
}

// ---------------- fused prep + edge partition (R13 structure) ----------------
#define SEG0 (N_PAD * 16)
#define SEG1 (SEG0 + 128 * 64)
#define SEG2 (SEG1 + 64 * 64)
#define PREP_TOT SEG2

__global__ void k_prep_part(const float* __restrict__ x,
                            const float* __restrict__ W1l, const float* __restrict__ W1r,
                            const float* __restrict__ W2l, const float* __restrict__ W2r,
                            const int* __restrict__ src, const int* __restrict__ dst,
                            u16* __restrict__ xb, u16* __restrict__ W1p,
                            u16* __restrict__ W2p, u32* __restrict__ region,
                            int* __restrict__ gcur) {
  if (blockIdx.x < NPART) {
    __shared__ int hist[256];
    __shared__ int base[256];
    const int t = threadIdx.x;
    hist[t] = 0;
    __syncthreads();
    const int e0 = blockIdx.x * ECHUNK;
    const int e1 = min(e0 + ECHUNK, N_EDGES);
    int dv[EPT], sv[EPT];
#pragma unroll
    for (int i = 0; i < EPT; ++i) {
      int e = e0 + t + i * 256;
      int ok = (e < e1);
      dv[i] = ok ? dst[e] : -1;
      sv[i] = ok ? src[e] : 0;
      if (ok) atomicAdd(&hist[dv[i] >> 8], 1);
    }
    __syncthreads();
    base[t] = (hist[t] > 0) ? atomicAdd(&gcur[t], hist[t]) : 0;
    hist[t] = 0;
    __syncthreads();
#pragma unroll
    for (int i = 0; i < EPT; ++i) {
      int d = dv[i];
      if (d >= 0) {
        int bin = d >> 8;
        int idx = base[bin] + atomicAdd(&hist[bin], 1);
        if (idx < BCAP)
          region[(size_t)bin * BCAP + idx] = (u32)(sv[i] & 0xffff) | ((u32)(d & 255) << 16);
      }
    }
    return;
  }
  int idx = (blockIdx.x - NPART) * 256 + threadIdx.x;
  if (idx < SEG0) {
    int row = idx >> 4;
    int c8 = (idx & 15) * 8;
    short8 o;
    if (row < N_NODES) {
      f32x4 a = *(const f32x4*)&x[(size_t)row * 128 + c8];
      f32x4 b = *(const f32x4*)&x[(size_t)row * 128 + c8 + 4];
      o[0] = (short)f2bf(a[0]); o[1] = (short)f2bf(a[1]);
      o[2] = (short)f2bf(a[2]); o[3] = (short)f2bf(a[3]);
      o[4] = (short)f2bf(b[0]); o[5] = (short)f2bf(b[1]);
      o[6] = (short)f2bf(b[2]); o[7] = (short)f2bf(b[3]);
    } else {
      for (int j = 0; j < 8; ++j) o[j] = 0;
    }
    *(short8*)&xb[(size_t)row * 128 + c8] = o;
  } else if (idx < SEG1) {
    int i = idx - SEG0;
    int F = i >> 6, l = i & 63;
    int wch = F >> 6, kt = (F >> 4) & 3, kk = (F >> 3) & 1, n = F & 7;
    int row = wch * 128 + n * 16 + (l & 15);
    int kb = kt * 64 + kk * 32 + (l >> 4) * 8;
    short8 o;
#pragma unroll
    for (int j = 0; j < 8; ++j) {
      int k = kb + j;
      float v = (k < 128) ? W1l[(size_t)k * HID + row] : W1r[(size_t)(k - 128) * HID + row];
      o[j] = (short)f2bf(v);
    }
    *(short8*)&W1p[(size_t)i * 8] = o;
  } else if (idx < SEG2) {
    int i = idx - SEG1;
    int G = i >> 6, l = i & 63;
    int wch = G >> 5, kk = (G >> 2) & 7, n = G & 3;
    int row = wch * 64 + n * 16 + (l & 15);
    int kb = kk * 32 + (l >> 4) * 8;
    short8 o;
#pragma unroll
    for (int j = 0; j < 8; ++j) {
      int k = kb + j;
      float v = (row < 64) ? W2l[(size_t)k * OUT_DIM + row]
                           : W2r[(size_t)k * OUT_DIM + (row - 64)];
      o[j] = (short)f2bf(v);
    }
    *(short8*)&W2p[(size_t)i * 8] = o;
  }
}

// ---------------- bucket build: one block per bin, LDS atomics only ----------------

__global__ __launch_bounds__(256) void k_build(const u32* __restrict__ region,
                                               const int* __restrict__ gcur,
                                               int* __restrict__ cnt,
                                               u16* __restrict__ bucket) {
  __shared__ u16 lbkt[256 * 64];
  __shared__ int lcnt[256];
  const int t = threadIdx.x;
  const int bin = blockIdx.x;
  lcnt[t] = 0;
  __syncthreads();
  int n = gcur[bin];
  if (n > BCAP) n = BCAP;
  for (int i = t; i < n; i += 256) {
    u32 r = region[(size_t)bin * BCAP + i];
    int dl = (r >> 16) & 255;
    int pos = atomicAdd(&lcnt[dl], 1);
    if (pos < MAX_DEG) lbkt[dl * 64 + pos] = (u16)(r & 0xffff);
  }
  __syncthreads();
  int gnode = bin * 256 + t;
  if (gnode < N_NODES) cnt[gnode] = lcnt[t];
  for (int i = t; i < 2048; i += 256) {
    int nl = i >> 3, sub = i & 7;
    int gn = bin * 256 + nl;
    if (gn < N_NODES)
      *(short8*)&bucket[(size_t)gn * 64 + sub * 8] = *(const short8*)&lbkt[nl * 64 + sub * 8];
  }
}

// ---------------- layer-1 mean aggregation: one wave per node ----------------

__global__ void k_agg(const u16* __restrict__ xb, const int* __restrict__ cnt,
                      const u16* __restrict__ bucket, u16* __restrict__ agg) {
  int node = blockIdx.x * 4 + (threadIdx.x >> 6);
  if (node >= N_PAD) return;
  int lane = threadIdx.x & 63;
  int es = lane >> 4, dl = lane & 15;
  int deg = (node < N_NODES) ? cnt[node] : 0;
  int sreg = (node < N_NODES) ? (int)bucket[(size_t)node * MAX_DEG + lane] : 0;
  float acc[8] = {0.f, 0.f, 0.f, 0.f, 0.f, 0.f, 0.f, 0.f};
  short8 pend = (short8){0, 0, 0, 0, 0, 0, 0, 0};
  for (int e = 0; e < deg; e += 4) {
    int ee = e + es;
    int s = __shfl(sreg, ee & 63);  // full-wave active (EXEC rule)
    short8 v = (short8){0, 0, 0, 0, 0, 0, 0, 0};
    if (ee < deg) v = *(const short8*)&xb[(size_t)s * 128 + dl * 8];
#pragma unroll
    for (int j = 0; j < 8; ++j) acc[j] += bf2f((u16)pend[j]);
    pend = v;
  }
#pragma unroll
  for (int j = 0; j < 8; ++j) acc[j] += bf2f((u16)pend[j]);
#pragma unroll
  for (int j = 0; j < 8; ++j) {
    acc[j] += __shfl_xor(acc[j], 16);
    acc[j] += __shfl_xor(acc[j], 32);
  }
  float inv = 1.f / fmaxf((float)deg, 1.f);
  if (es == 0) {
    short8 o;
#pragma unroll
    for (int j = 0; j < 8; ++j) o[j] = (short)f2bf(acc[j] * inv);
    *(short8*)&agg[(size_t)node * 128 + dl * 8] = o;
  }
}

// ---------------- fused MLP ----------------

__device__ __forceinline__ void gl_lds16(const void* g, void* l) {
  __builtin_amdgcn_global_load_lds((const __attribute__((address_space(1))) u32*)g,
                                   (__attribute__((address_space(3))) u32*)l, 16, 0, 0);
}

__global__ __launch_bounds__(256, 3) void k_mlp(
    const u16* __restrict__ agg, const u16* __restrict__ xb,
    const u16* __restrict__ W1p, const u16* __restrict__ W2p,
    const float* __restrict__ b1, u16* __restrict__ pb, u16* __restrict__ qb) {
  __shared__ u16 hs[64 * 256];
  __shared__ u16 As[2][64 * 64];
  const int t = threadIdx.x;
  const int wave = t >> 6;
  const int lane = t & 63;
  const int brow = blockIdx.x * 64;
  const int lr = lane & 15;
  const int kg = lane >> 4;
  const int wch = wave & 1;

  const int wr = (wave >> 1) * 32;
  const int wc = wch * 128;

  f32x4 acc[2][8];
#pragma unroll
  for (int m = 0; m < 2; ++m)
#pragma unroll
    for (int n = 0; n < 8; ++n) acc[m][n] = (f32x4){0.f, 0.f, 0.f, 0.f};

  auto stageA = [&](int buf, int kt) {
    const u16* base = (kt < 2) ? agg : xb;
    const int koff = (kt & 1) * 64;
#pragma unroll
    for (int i = 0; i < 2; ++i) {
      int chunk = wave * 2 + i;
      int f = chunk * 1024 + lane * 16;
      int row = f >> 7;
      int cbs = (f & 127) ^ ((row & 7) << 4);
      gl_lds16(&base[(size_t)(brow + row) * 128 + koff + (cbs >> 1)],
               (char*)As[buf] + chunk * 1024);
    }
  };

  stageA(0, 0);
  __syncthreads();

#pragma unroll
  for (int kt = 0; kt < 4; ++kt) {
    const int cur = kt & 1;
    if (kt < 3) stageA(cur ^ 1, kt + 1);
#pragma unroll
    for (int kk = 0; kk < 2; ++kk) {
      short8 af[2], bfr[8];
      const int cb = kk * 64 + kg * 16;
#pragma unroll
      for (int m = 0; m < 2; ++m) {
        int row = wr + m * 16 + lr;
        af[m] = *(const short8*)((const char*)As[cur] + row * 128 + (cb ^ ((row & 7) << 4)));
      }
#pragma unroll
      for (int n = 0; n < 8; ++n)
        bfr[n] = *(const short8*)&W1p[(size_t)(((wch * 4 + kt) * 2 + kk) * 8 + n) * 512 +
                                      lane * 8];
#pragma unroll
      for (int m = 0; m < 2; ++m)
#pragma unroll
        for (int n = 0; n < 8; ++n)
          acc[m][n] =
              __builtin_amdgcn_mfma_f32_16x16x32_bf16(af[m], bfr[n], acc[m][n], 0, 0, 0);
    }
    __syncthreads();
  }

#pragma unroll
  for (int n = 0; n < 8; ++n) {
    int col = wc + n * 16 + lr;
    float bv = b1[col];
#pragma unroll
    for (int m = 0; m < 2; ++m) {
#pragma unroll
      for (int j = 0; j < 4; ++j) {
        int row = wr + kg * 4 + m * 16 + j;
        float v = fmaxf(acc[m][n][j] + bv, 0.f);
        *(u16*)((char*)hs + row * 512 + ((col * 2) ^ ((row & 7) << 4))) = f2bf(v);
      }
    }
  }
  __syncthreads();

  const int wr2 = (wave >> 1) * 32;
  f32x4 acc2[2][4];
#pragma unroll
  for (int m = 0; m < 2; ++m)
#pragma unroll
    for (int n = 0; n < 4; ++n) acc2[m][n] = (f32x4){0.f, 0.f, 0.f, 0.f};

#pragma unroll
  for (int kk = 0; kk < 8; ++kk) {
    const int cb = kk * 64 + kg * 16;
    short8 af[2], bfr[4];
#pragma unroll
    for (int m = 0; m < 2; ++m) {
      int row = wr2 + m * 16 + lr;
      af[m] = *(const short8*)((const char*)hs + row * 512 + (cb ^ ((row & 7) << 4)));
    }
#pragma unroll
    for (int n = 0; n < 4; ++n)
      bfr[n] = *(const short8*)&W2p[(size_t)((wch * 8 + kk) * 4 + n) * 512 + lane * 8];
#pragma unroll
    for (int m = 0; m < 2; ++m)
#pragma unroll
      for (int n = 0; n < 4; ++n)
        acc2[m][n] =
            __builtin_amdgcn_mfma_f32_16x16x32_bf16(af[m], bfr[n], acc2[m][n], 0, 0, 0);
  }

  u16* outb = wch ? qb : pb;
#pragma unroll
  for (int n = 0; n < 4; ++n) {
    int col = n * 16 + lr;
#pragma unroll
    for (int m = 0; m < 2; ++m) {
#pragma unroll
      for (int j = 0; j < 4; ++j) {
        int row = brow + wr2 + kg * 4 + m * 16 + j;
        outb[(size_t)row * 64 + col] = f2bf(acc2[m][n][j]);
      }
    }
  }
}

// ---------------- output: out = mean_agg(pb) + qb + b2, one wave per node ----------------

__global__ void k_out(const u16* __restrict__ pb, const u16* __restrict__ qb,
                      const int* __restrict__ cnt, const u16* __restrict__ bucket,
                      const float* __restrict__ b2, float* __restrict__ out) {
  int node = blockIdx.x * 4 + (threadIdx.x >> 6);
  if (node >= N_NODES) return;
  int lane = threadIdx.x & 63;
  int es = lane >> 3, dl = lane & 7;
  int deg = cnt[node];
  int sreg = (int)bucket[(size_t)node * MAX_DEG + lane];
  float acc[8] = {0.f, 0.f, 0.f, 0.f, 0.f, 0.f, 0.f, 0.f};
  short8 pend = (short8){0, 0, 0, 0, 0, 0, 0, 0};
  for (int e = 0; e < deg; e += 8) {
    int ee = e + es;
    int s = __shfl(sreg, ee & 63);  // full-wave active
    short8 v = (short8){0, 0, 0, 0, 0, 0, 0, 0};
    if (ee < deg) v = *(const short8*)&pb[(size_t)s * 64 + dl * 8];
#pragma unroll
    for (int j = 0; j < 8; ++j) acc[j] += bf2f((u16)pend[j]);
    pend = v;
  }
#pragma unroll
  for (int j = 0; j < 8; ++j) acc[j] += bf2f((u16)pend[j]);
#pragma unroll
  for (int j = 0; j < 8; ++j) {
    acc[j] += __shfl_xor(acc[j], 8);
    acc[j] += __shfl_xor(acc[j], 16);
    acc[j] += __shfl_xor(acc[j], 32);
  }
  float inv = 1.f / fmaxf((float)deg, 1.f);
  if (es == 0) {
    short8 q = *(const short8*)&qb[(size_t)node * 64 + dl * 8];
    f32x4 bb0 = *(const f32x4*)&b2[dl * 8];
    f32x4 bb1 = *(const f32x4*)&b2[dl * 8 + 4];
    f32x4 o0, o1;
#pragma unroll
    for (int j = 0; j < 4; ++j) {
      o0[j] = acc[j] * inv + bf2f((u16)q[j]) + bb0[j];
      o1[j] = acc[j + 4] * inv + bf2f((u16)q[j + 4]) + bb1[j];
    }
    *(f32x4*)&out[(size_t)node * 64 + dl * 8] = o0;
    *(f32x4*)&out[(size_t)node * 64 + dl * 8 + 4] = o1;
  }
}

// ---------------- launch ----------------

extern "C" void kernel_launch(void* const* d_in, const int* in_sizes, int n_in,
                              void* d_out, int out_size, void* d_ws, size_t ws_size,
                              hipStream_t stream) {
  const float* x   = (const float*)d_in[0];
  const int*   ei  = (const int*)d_in[1];
  const float* W1l = (const float*)d_in[2];
  const float* W1r = (const float*)d_in[3];
  const float* b1  = (const float*)d_in[4];
  const float* W2l = (const float*)d_in[5];
  const float* W2r = (const float*)d_in[6];
  const float* b2  = (const float*)d_in[7];
  float* out = (float*)d_out;

  const int* src = ei;
  const int* dst = ei + N_EDGES;

  char* ws = (char*)d_ws;
  size_t off = 0;
  auto alloc = [&](size_t bytes) -> void* {
    void* p = ws + off;
    off = (off + bytes + 255) & ~(size_t)255;
    return p;
  };
  int* gcur   = (int*)alloc(256 * 4);
  u32* region = (u32*)alloc((size_t)NBINS * BCAP * 4);
  int* cnt    = (int*)alloc((size_t)N_NODES * 4);
  u16* bucket = (u16*)alloc((size_t)N_NODES * MAX_DEG * 2);
  u16* xb     = (u16*)alloc((size_t)N_PAD * 128 * 2);
  u16* agg    = (u16*)alloc((size_t)N_PAD * 128 * 2);
  u16* W1p    = (u16*)alloc((size_t)128 * 64 * 8 * 2);
  u16* W2p    = (u16*)alloc((size_t)64 * 64 * 8 * 2);
  u16* pb     = (u16*)alloc((size_t)N_PAD * 64 * 2);
  u16* qb     = (u16*)alloc((size_t)N_PAD * 64 * 2);

  k_zero_gcur<<<1, 256, 0, stream>>>(gcur);

  int blocks = NPART + (PREP_TOT + 255) / 256;
  k_prep_part<<<blocks, 256, 0, stream>>>(x, W1l, W1r, W2l, W2r, src, dst,
                                          xb, W1p, W2p, region, gcur);
  k_build<<<NBINS, 256, 0, stream>>>(region, gcur, cnt, bucket);
  k_agg<<<N_PAD / 4, 256, 0, stream>>>(xb, cnt, bucket, agg);
  k_mlp<<<N_PAD / 64, 256, 0, stream>>>(agg, xb, W1p, W2p, b1, pb, qb);
  k_out<<<(N_NODES + 3) / 4, 256, 0, stream>>>(pb, qb, cnt, bucket, b2, out);
}